// Round 2
// baseline (163.043 us; speedup 1.0000x reference)
//
#include <hip/hip_runtime.h>
#include <cstddef>

#define BS_   4
#define CH_   3
#define HH    512
#define WW    512
#define KS    11
#define K2_   (KS*KS)          // 121
#define HW_   (HH*WW)          // 262144
#define PADL  5
#define PADR  11
#define PW_   (PADL + WW + PADR)  // 528 -> row stride 2112 B, 16B-aligned
#define PX    4                // pixels per thread in x

// ---------------------------------------------------------------------------
// Pad data in x into d_ws: [BS][CH][H][PW_], zero outside [PADL, PADL+W).
// Rewritten fully every call (d_ws is poisoned once, never re-poisoned).
// ---------------------------------------------------------------------------
__global__ void pad_data_kernel(const float* __restrict__ data,
                                float* __restrict__ dpad) {
  int idx = blockIdx.x * 256 + threadIdx.x;
  const int total = BS_ * CH_ * HH * PW_;
  if (idx >= total) return;
  int col  = idx % PW_;
  int rest = idx / PW_;            // (b*CH + c)*H + row
  int sc   = col - PADL;
  float v = 0.0f;
  if (sc >= 0 && sc < WW) v = data[(size_t)rest * WW + sc];
  dpad[idx] = v;
}

// ---------------------------------------------------------------------------
// Fused ProgressiveKernelApply update.
// One thread = 4 consecutive x-pixels. Single pass over the 121 kernel taps:
//   m      = running max of raw kernel values (all taps, unconditional)
//   sw     = sum of exp(k) * x-validity            (valid rows only)
//   sr[c]  = sum of exp(k) * data[neighbor]        (valid rows only)
// Epilogue: new_max = max(m, max_w); factor exp(-new_max) into sw/sr;
//           scaler = exp(max_w - new_max) rescales the old accumulators.
// ---------------------------------------------------------------------------
template<bool PADDED>
__global__ void pka_kernel(const float* __restrict__ kern,
                           const float* __restrict__ data,
                           const float* __restrict__ dpad,
                           const float* __restrict__ sum_r_in,
                           const float* __restrict__ sum_w_in,
                           const float* __restrict__ max_w_in,
                           float* __restrict__ out) {
  const int tx = threadIdx.x;                 // 0..63
  const int ty = threadIdx.y;                 // 0..3  (wave-uniform rows)
  const int X  = blockIdx.x * (64 * PX) + tx * PX;  // base output col
  const int y  = blockIdx.y * 4 + ty;
  const int b  = blockIdx.z;

  // x-validity mask per window index j (source col = X-5+j), j = dx + p
  float vld[14];
  int colc[14];
  #pragma unroll
  for (int j = 0; j < 14; ++j) {
    int col = X - PADL + j;
    vld[j] = (col >= 0 && col < WW) ? 1.0f : 0.0f;
    if constexpr (!PADDED) colc[j] = min(max(col, 0), WW - 1);
    else colc[j] = 0;
  }

  float m0 = -3.0e38f, m1 = -3.0e38f, m2 = -3.0e38f, m3 = -3.0e38f;
  float sw0 = 0.f, sw1 = 0.f, sw2 = 0.f, sw3 = 0.f;
  float sr[CH_][PX];
  #pragma unroll
  for (int c = 0; c < CH_; ++c)
    #pragma unroll
    for (int p = 0; p < PX; ++p) sr[c][p] = 0.f;

  const float* kb = kern + (((size_t)b * K2_) * HH + y) * WW + X;

  #pragma unroll 1
  for (int dy = 0; dy < KS; ++dy) {
    // --- load 11 float4 kernel taps for this dy (coalesced 16B/lane) ---
    float4 kv[KS];
    #pragma unroll
    for (int dx = 0; dx < KS; ++dx)
      kv[dx] = *reinterpret_cast<const float4*>(kb + (size_t)(dy * KS + dx) * HW_);

    // --- running max over ALL taps (reference kmax is unconditional) ---
    #pragma unroll
    for (int dx = 0; dx < KS; ++dx) {
      m0 = fmaxf(m0, kv[dx].x);
      m1 = fmaxf(m1, kv[dx].y);
      m2 = fmaxf(m2, kv[dx].z);
      m3 = fmaxf(m3, kv[dx].w);
    }

    const int sy = y + dy - PADL;
    if (sy >= 0 && sy < HH) {        // wave-uniform (ty uniform per wave)
      // exp in place
      #pragma unroll
      for (int dx = 0; dx < KS; ++dx) {
        kv[dx].x = __expf(kv[dx].x);
        kv[dx].y = __expf(kv[dx].y);
        kv[dx].z = __expf(kv[dx].z);
        kv[dx].w = __expf(kv[dx].w);
      }
      // sum_w: validity-masked accumulate
      #pragma unroll
      for (int dx = 0; dx < KS; ++dx) {
        sw0 += kv[dx].x * vld[dx + 0];
        sw1 += kv[dx].y * vld[dx + 1];
        sw2 += kv[dx].z * vld[dx + 2];
        sw3 += kv[dx].w * vld[dx + 3];
      }
      // sum_r per channel
      #pragma unroll
      for (int c = 0; c < CH_; ++c) {
        float d[16];
        if constexpr (PADDED) {
          const float* rp = dpad + (((size_t)b * CH_ + c) * HH + sy) * PW_ + X;
          float4 a0 = *reinterpret_cast<const float4*>(rp);
          float4 a1 = *reinterpret_cast<const float4*>(rp + 4);
          float4 a2 = *reinterpret_cast<const float4*>(rp + 8);
          float4 a3 = *reinterpret_cast<const float4*>(rp + 12);
          d[0]=a0.x; d[1]=a0.y; d[2]=a0.z;  d[3]=a0.w;
          d[4]=a1.x; d[5]=a1.y; d[6]=a1.z;  d[7]=a1.w;
          d[8]=a2.x; d[9]=a2.y; d[10]=a2.z; d[11]=a2.w;
          d[12]=a3.x; d[13]=a3.y; d[14]=a3.z; d[15]=a3.w;
        } else {
          const float* rp = data + (((size_t)b * CH_ + c) * HH + sy) * WW;
          #pragma unroll
          for (int j = 0; j < 14; ++j) d[j] = rp[colc[j]] * vld[j];
          d[14] = 0.f; d[15] = 0.f;
        }
        #pragma unroll
        for (int dx = 0; dx < KS; ++dx) {
          sr[c][0] += kv[dx].x * d[dx + 0];
          sr[c][1] += kv[dx].y * d[dx + 1];
          sr[c][2] += kv[dx].z * d[dx + 2];
          sr[c][3] += kv[dx].w * d[dx + 3];
        }
      }
    }
  }

  // ------------------------------- epilogue -------------------------------
  const size_t pix = ((size_t)b * HH + y) * WW + X;
  float4 mw  = *reinterpret_cast<const float4*>(max_w_in + pix);
  float4 swi = *reinterpret_cast<const float4*>(sum_w_in + pix);

  float nm0 = fmaxf(m0, mw.x), nm1 = fmaxf(m1, mw.y);
  float nm2 = fmaxf(m2, mw.z), nm3 = fmaxf(m3, mw.w);
  float sc0 = __expf(mw.x - nm0), sc1 = __expf(mw.y - nm1);
  float sc2 = __expf(mw.z - nm2), sc3 = __expf(mw.w - nm3);
  float iv0 = __expf(-nm0), iv1 = __expf(-nm1);
  float iv2 = __expf(-nm2), iv3 = __expf(-nm3);

  // sum_r outputs
  #pragma unroll
  for (int c = 0; c < CH_; ++c) {
    const size_t off = (((size_t)b * CH_ + c) * HH + y) * WW + X;
    float4 sri = *reinterpret_cast<const float4*>(sum_r_in + off);
    float4 o;
    o.x = sri.x * sc0 + sr[c][0] * iv0;
    o.y = sri.y * sc1 + sr[c][1] * iv1;
    o.z = sri.z * sc2 + sr[c][2] * iv2;
    o.w = sri.w * sc3 + sr[c][3] * iv3;
    *reinterpret_cast<float4*>(out + off) = o;
  }
  // sum_w output
  {
    float4 o;
    o.x = swi.x * sc0 + sw0 * iv0;
    o.y = swi.y * sc1 + sw1 * iv1;
    o.z = swi.z * sc2 + sw2 * iv2;
    o.w = swi.w * sc3 + sw3 * iv3;
    *reinterpret_cast<float4*>(out + (size_t)BS_ * CH_ * HW_ + pix) = o;
  }
  // new_max output
  {
    float4 o; o.x = nm0; o.y = nm1; o.z = nm2; o.w = nm3;
    *reinterpret_cast<float4*>(out + (size_t)BS_ * CH_ * HW_ + (size_t)BS_ * HW_ + pix) = o;
  }
}

// ---------------------------------------------------------------------------
extern "C" void kernel_launch(void* const* d_in, const int* in_sizes, int n_in,
                              void* d_out, int out_size, void* d_ws, size_t ws_size,
                              hipStream_t stream) {
  const float* data  = (const float*)d_in[0];
  const float* kern  = (const float*)d_in[1];
  const float* sum_r = (const float*)d_in[2];
  const float* sum_w = (const float*)d_in[3];
  const float* max_w = (const float*)d_in[4];
  float* out = (float*)d_out;

  dim3 block(64, 4, 1);
  dim3 grid(WW / (64 * PX), HH / 4, BS_);   // 2 x 128 x 4 = 1024 blocks

  const size_t padded_bytes = (size_t)BS_ * CH_ * HH * PW_ * sizeof(float);
  if (ws_size >= padded_bytes) {
    float* dpad = (float*)d_ws;
    const int total = BS_ * CH_ * HH * PW_;
    pad_data_kernel<<<(total + 255) / 256, 256, 0, stream>>>(data, dpad);
    pka_kernel<true><<<grid, block, 0, stream>>>(kern, data, dpad, sum_r,
                                                 sum_w, max_w, out);
  } else {
    pka_kernel<false><<<grid, block, 0, stream>>>(kern, data, nullptr, sum_r,
                                                  sum_w, max_w, out);
  }
}

// Round 5
// 145.656 us; speedup vs baseline: 1.1194x; 1.1194x over previous
//
#include <hip/hip_runtime.h>
#include <cstddef>

#define BS_   4
#define CH_   3
#define HH    512
#define WW    512
#define KS    11
#define K2_   (KS*KS)          // 121
#define HW_   (HH*WW)          // 262144
#define PADL  5
#define PADR  11
#define PW_   (PADL + WW + PADR)  // 528 -> row stride 2112 B, 16B-aligned
#define PX    4                // pixels per thread in x

typedef float f4 __attribute__((ext_vector_type(4)));  // native vec: OK for
                                                       // __builtin_nontemporal_*

// ---------------------------------------------------------------------------
// Pad data in x into d_ws: [BS][CH][H][PW_], zero outside [PADL, PADL+W).
// Rewritten fully every call (d_ws is poisoned once, never re-poisoned).
// ---------------------------------------------------------------------------
__global__ void pad_data_kernel(const float* __restrict__ data,
                                float* __restrict__ dpad) {
  int idx = blockIdx.x * 256 + threadIdx.x;
  const int total = BS_ * CH_ * HH * PW_;
  if (idx >= total) return;
  int col  = idx % PW_;
  int rest = idx / PW_;            // (b*CH + c)*H + row
  int sc   = col - PADL;
  float v = 0.0f;
  if (sc >= 0 && sc < WW) v = data[(size_t)rest * WW + sc];
  dpad[idx] = v;
}

// ---------------------------------------------------------------------------
// Fused ProgressiveKernelApply update. One thread = 4 consecutive x-pixels.
// Single pass over the 121 kernel taps using exp(k-nm) = exp(k)*exp(-nm):
//   m      = running max of raw kernel values (all taps, unconditional)
//   sw     = sum of exp(k) * x-validity            (valid rows only)
//   sr[c]  = sum of exp(k) * data[neighbor]        (valid rows only)
// Epilogue folds in exp(-new_max) and rescales old accumulators.
//
// __launch_bounds__(128,4): cap VGPR at 128 so 4 waves/SIMD stay resident
// (at >128 VGPR residency halves to 2/SIMD and the 11 batched tap loads
// per dy can no longer be latency-hidden).
// ---------------------------------------------------------------------------
template<bool PADDED>
__global__ __launch_bounds__(128, 4)
void pka_kernel(const float* __restrict__ kern,
                const float* __restrict__ data,
                const float* __restrict__ dpad,
                const float* __restrict__ sum_r_in,
                const float* __restrict__ sum_w_in,
                const float* __restrict__ max_w_in,
                float* __restrict__ out) {
  const int tx = threadIdx.x;                 // 0..63
  const int ty = threadIdx.y;                 // 0..1 (wave-uniform rows)
  const int X  = blockIdx.x * (64 * PX) + tx * PX;  // base output col
  const int y  = blockIdx.y * 2 + ty;
  const int b  = blockIdx.z;

  // x-validity mask per window index j (source col = X-5+j), j = dx + p
  float vld[14];
  int colc[14];
  #pragma unroll
  for (int j = 0; j < 14; ++j) {
    int col = X - PADL + j;
    vld[j] = (col >= 0 && col < WW) ? 1.0f : 0.0f;
    if constexpr (!PADDED) colc[j] = min(max(col, 0), WW - 1);
    else colc[j] = 0;
  }

  float m0 = -3.0e38f, m1 = -3.0e38f, m2 = -3.0e38f, m3 = -3.0e38f;
  float sw0 = 0.f, sw1 = 0.f, sw2 = 0.f, sw3 = 0.f;
  float sr[CH_][PX];
  #pragma unroll
  for (int c = 0; c < CH_; ++c)
    #pragma unroll
    for (int p = 0; p < PX; ++p) sr[c][p] = 0.f;

  const float* kb = kern + (((size_t)b * K2_) * HH + y) * WW + X;

  #pragma unroll 1
  for (int dy = 0; dy < KS; ++dy) {
    // --- load 11 x 16B kernel taps for this dy (coalesced, nontemporal:
    //     507 MB read-once stream must not evict dpad from L2) ---
    f4 kv[KS];
    #pragma unroll
    for (int dx = 0; dx < KS; ++dx)
      kv[dx] = __builtin_nontemporal_load(
          reinterpret_cast<const f4*>(kb + (size_t)(dy * KS + dx) * HW_));

    // --- running max over ALL taps (reference kmax is unconditional) ---
    #pragma unroll
    for (int dx = 0; dx < KS; ++dx) {
      m0 = fmaxf(m0, kv[dx].x);
      m1 = fmaxf(m1, kv[dx].y);
      m2 = fmaxf(m2, kv[dx].z);
      m3 = fmaxf(m3, kv[dx].w);
    }

    const int sy = y + dy - PADL;
    if (sy >= 0 && sy < HH) {        // wave-uniform (ty uniform per wave)
      // exp in place
      #pragma unroll
      for (int dx = 0; dx < KS; ++dx) {
        kv[dx].x = __expf(kv[dx].x);
        kv[dx].y = __expf(kv[dx].y);
        kv[dx].z = __expf(kv[dx].z);
        kv[dx].w = __expf(kv[dx].w);
      }
      // sum_w: validity-masked accumulate
      #pragma unroll
      for (int dx = 0; dx < KS; ++dx) {
        sw0 += kv[dx].x * vld[dx + 0];
        sw1 += kv[dx].y * vld[dx + 1];
        sw2 += kv[dx].z * vld[dx + 2];
        sw3 += kv[dx].w * vld[dx + 3];
      }
      // sum_r per channel (d[16] is transient; reused across channels)
      #pragma unroll
      for (int c = 0; c < CH_; ++c) {
        float d[16];
        if constexpr (PADDED) {
          const float* rp = dpad + (((size_t)b * CH_ + c) * HH + sy) * PW_ + X;
          f4 a0 = *reinterpret_cast<const f4*>(rp);
          f4 a1 = *reinterpret_cast<const f4*>(rp + 4);
          f4 a2 = *reinterpret_cast<const f4*>(rp + 8);
          f4 a3 = *reinterpret_cast<const f4*>(rp + 12);
          d[0]=a0.x; d[1]=a0.y; d[2]=a0.z;  d[3]=a0.w;
          d[4]=a1.x; d[5]=a1.y; d[6]=a1.z;  d[7]=a1.w;
          d[8]=a2.x; d[9]=a2.y; d[10]=a2.z; d[11]=a2.w;
          d[12]=a3.x; d[13]=a3.y; d[14]=a3.z; d[15]=a3.w;
        } else {
          const float* rp = data + (((size_t)b * CH_ + c) * HH + sy) * WW;
          #pragma unroll
          for (int j = 0; j < 14; ++j) d[j] = rp[colc[j]] * vld[j];
          d[14] = 0.f; d[15] = 0.f;
        }
        #pragma unroll
        for (int dx = 0; dx < KS; ++dx) {
          sr[c][0] += kv[dx].x * d[dx + 0];
          sr[c][1] += kv[dx].y * d[dx + 1];
          sr[c][2] += kv[dx].z * d[dx + 2];
          sr[c][3] += kv[dx].w * d[dx + 3];
        }
      }
    }
  }

  // ------------------------------- epilogue -------------------------------
  const size_t pix = ((size_t)b * HH + y) * WW + X;
  f4 mw  = *reinterpret_cast<const f4*>(max_w_in + pix);
  f4 swi = *reinterpret_cast<const f4*>(sum_w_in + pix);

  float nm0 = fmaxf(m0, mw.x), nm1 = fmaxf(m1, mw.y);
  float nm2 = fmaxf(m2, mw.z), nm3 = fmaxf(m3, mw.w);
  float sc0 = __expf(mw.x - nm0), sc1 = __expf(mw.y - nm1);
  float sc2 = __expf(mw.z - nm2), sc3 = __expf(mw.w - nm3);
  float iv0 = __expf(-nm0), iv1 = __expf(-nm1);
  float iv2 = __expf(-nm2), iv3 = __expf(-nm3);

  // sum_r outputs (write-once -> nontemporal)
  #pragma unroll
  for (int c = 0; c < CH_; ++c) {
    const size_t off = (((size_t)b * CH_ + c) * HH + y) * WW + X;
    f4 sri = *reinterpret_cast<const f4*>(sum_r_in + off);
    f4 o;
    o.x = sri.x * sc0 + sr[c][0] * iv0;
    o.y = sri.y * sc1 + sr[c][1] * iv1;
    o.z = sri.z * sc2 + sr[c][2] * iv2;
    o.w = sri.w * sc3 + sr[c][3] * iv3;
    __builtin_nontemporal_store(o, reinterpret_cast<f4*>(out + off));
  }
  // sum_w output
  {
    f4 o;
    o.x = swi.x * sc0 + sw0 * iv0;
    o.y = swi.y * sc1 + sw1 * iv1;
    o.z = swi.z * sc2 + sw2 * iv2;
    o.w = swi.w * sc3 + sw3 * iv3;
    __builtin_nontemporal_store(
        o, reinterpret_cast<f4*>(out + (size_t)BS_ * CH_ * HW_ + pix));
  }
  // new_max output
  {
    f4 o; o.x = nm0; o.y = nm1; o.z = nm2; o.w = nm3;
    __builtin_nontemporal_store(
        o, reinterpret_cast<f4*>(out + (size_t)BS_ * CH_ * HW_ +
                                 (size_t)BS_ * HW_ + pix));
  }
}

// ---------------------------------------------------------------------------
extern "C" void kernel_launch(void* const* d_in, const int* in_sizes, int n_in,
                              void* d_out, int out_size, void* d_ws, size_t ws_size,
                              hipStream_t stream) {
  const float* data  = (const float*)d_in[0];
  const float* kern  = (const float*)d_in[1];
  const float* sum_r = (const float*)d_in[2];
  const float* sum_w = (const float*)d_in[3];
  const float* max_w = (const float*)d_in[4];
  float* out = (float*)d_out;

  dim3 block(64, 2, 1);
  dim3 grid(WW / (64 * PX), HH / 2, BS_);   // 2 x 256 x 4 = 2048 blocks

  const size_t padded_bytes = (size_t)BS_ * CH_ * HH * PW_ * sizeof(float);
  if (ws_size >= padded_bytes) {
    float* dpad = (float*)d_ws;
    const int total = BS_ * CH_ * HH * PW_;
    pad_data_kernel<<<(total + 255) / 256, 256, 0, stream>>>(data, dpad);
    pka_kernel<true><<<grid, block, 0, stream>>>(kern, data, dpad, sum_r,
                                                 sum_w, max_w, out);
  } else {
    pka_kernel<false><<<grid, block, 0, stream>>>(kern, data, nullptr, sum_r,
                                                  sum_w, max_w, out);
  }
}